// Round 13
// baseline (112.572 us; speedup 1.0000x reference)
//
#include <hip/hip_runtime.h>
#include <hip/hip_bf16.h>

// SocialPooling round 13: phase-overlap restructure.
// Evidence: R8/R10/R11/R12 all 104-107us (inner-loop tweaks neutral) with all
// pipes idle -> K1 is serialized-phase latency-bound at 1 block/CU (both
// waves/SIMD share the same barriers). Fix: split each sequence's cells over
// 2 blocks (grid 512 x 256thr, 4 waves x 8 cells; per-wave work and Wt
// traffic unchanged) so each CU runs 2 INDEPENDENT blocks whose phases
// interleave. K1 writes partial X (ws); K2 adds halves + bias -> X + column
// partials; K3 = verified sp_finish. Cell loop is the verified R8/R10 body.

#define NSEQ 256
#define NTOT (NSEQ*64)
#define EPSV 1e-5f

typedef __attribute__((ext_vector_type(8))) short short8;
typedef __attribute__((ext_vector_type(4))) float f32x4;
typedef unsigned short ushort_t;

__device__ __forceinline__ ushort_t f2b(float f) {
    __hip_bfloat16 h = __float2bfloat16(f);                 // RNE
    return *reinterpret_cast<ushort_t*>(&h);
}
__device__ __forceinline__ unsigned pk2(float a, float b) { // 2x f32 -> packed bf16x2 (RNE)
    __hip_bfloat162 t = __float22bfloat162_rn(float2{a, b});
    return *reinterpret_cast<unsigned*>(&t);
}
__device__ __forceinline__ int kperm(int k) {               // slot -> source kf
    return ((k >> 5)*2 + ((k & 7) >> 2))*16 + ((k >> 3) & 3)*4 + (k & 3);
}

// ---------------- K0: W -> bf16 Wt'[g][col][slot] = W[g*64 + pi(slot)][col] ----------------
__global__ __launch_bounds__(256) void sp_transpose(
    const float* __restrict__ W, short* __restrict__ Wt)
{
    __shared__ __align__(16) float Tl[64*68];
    const int b = blockIdx.x, tid = threadIdx.x;
    const float* wg = W + (size_t)b*4096;
    for (int m = 0; m < 4; ++m) {
        int c = m*256 + tid;
        int k = c >> 4, t0 = (c & 15)*4;
        *(f32x4*)(Tl + k*68 + t0) = *(const f32x4*)(wg + k*64 + t0);
    }
    __syncthreads();
    for (int m = 0; m < 2; ++m) {
        int q = m*256 + tid;
        int col = q >> 3, k0 = (q & 7)*8;
        short8 o;
        #pragma unroll
        for (int i2 = 0; i2 < 8; ++i2)
            o[i2] = (short)f2b(Tl[kperm(k0 + i2)*68 + col]);
        *(short8*)(Wt + ((size_t)(b*64 + col)*64 + k0)) = o;
    }
}

// ---------------- K1: main (block = seq-half of cells) ----------------
// LDS: staging {Ht u16[64][72]@0 9216, cm@9216 4096, pos@13312 512} aliased by
//      Xs0 f32[64][68]@0 (17408); Xs1@17408 (17408). Total 34816 -> 2 blocks/CU.
#define SM_CM   9216
#define SM_POS  13312
#define SM_XS1  17408
#define SM_TOT  34816

__global__ __launch_bounds__(256, 2) void sp_main(
    const float* __restrict__ h, const float* __restrict__ pos,
    const short* __restrict__ Wt, float* __restrict__ Xpart)
{
    __shared__ __align__(16) char smem[SM_TOT];
    ushort_t*      Ht = (ushort_t*)(smem);
    unsigned char* cm = (unsigned char*)(smem + SM_CM);
    float*         px = (float*)(smem + SM_POS);
    float*         py = px + 64;

    const int b     = blockIdx.x;
    const int s     = b >> 1;           // sequence
    const int chalf = b & 1;            // cell half: cells chalf*32 .. +31
    const int base  = s * 64;
    const int tid   = threadIdx.x;
    const int lane  = tid & 63, w = tid >> 6;     // 4 waves; wave owns 8 cells
    const int ln15  = lane & 15, ln4 = lane >> 4;
    const int xph   = (b >> 3) & 7;     // stagger: varies within an XCD (R8 win)

    if (tid < 64) { px[tid] = pos[(base + tid)*2]; py[tid] = pos[(base + tid)*2 + 1]; }
    // issue h loads into registers up front; cellmap VALU below hides the latency
    f32x4 hreg[4];
    #pragma unroll
    for (int m = 0; m < 4; ++m) {
        int c = m*256 + tid;                       // 1024 f32x4 chunks
        int j = c >> 4, t0 = (c & 15)*4;
        hreg[m] = *(const f32x4*)(h + (size_t)(base + j)*64 + t0);
    }
    __syncthreads();                               // px/py visible

    // cellmap: cm[i][j] = cell 0..63 if valid pair else 255 (verified R1..R12)
    for (int m = 0; m < 16; ++m) {
        int p = m*256 + tid;
        int i = p >> 6, j = p & 63;
        unsigned char val = 255;
        if (i != j) {
            float ax = px[i], ay = py[i], ox = px[j], oy = py[j];
            float tlx = ax - 1.0f, tly = ay + 1.0f, brx = ax + 1.0f, bry = ay - 1.0f;
            bool oob = (ox >= brx) | (ox <= tlx) | (oy >= tly) | (oy <= bry);
            if (!oob) {
                int g = (int)(floorf((ox - tlx)*4.0f) + floorf((tly - oy)*4.0f)*8.0f);
                g = g < 0 ? 0 : (g > 63 ? 63 : g);
                val = (unsigned char)g;
            }
        }
        cm[i*64 + j] = val;
    }
    // stage H transposed: Ht[kf][j] = bf16(H[j][kf])
    #pragma unroll
    for (int m = 0; m < 4; ++m) {
        int c = m*256 + tid;
        int j = c >> 4, t0 = (c & 15)*4;
        #pragma unroll
        for (int u = 0; u < 4; ++u) Ht[(t0 + u)*72 + j] = f2b(hreg[m][u]);
    }
    __syncthreads();                               // cm + Ht visible

    // hoist GEMM1' A-frags (H^T rows) and the full cellmap for all 4 row-tiles
    short8 hf2[4][2];
    #pragma unroll
    for (int mt = 0; mt < 4; ++mt)
        #pragma unroll
        for (int kt2 = 0; kt2 < 2; ++kt2)
            hf2[mt][kt2] = *(const short8*)(Ht + (mt*16 + ln15)*72 + kt2*32 + ln4*8);
    unsigned cmv[4][2][2];
    #pragma unroll
    for (int rt = 0; rt < 4; ++rt)
        #pragma unroll
        for (int kt = 0; kt < 2; ++kt) {
            const unsigned* cp = (const unsigned*)(cm + (rt*16 + ln15)*64 + kt*32 + ln4*8);
            cmv[rt][kt][0] = cp[0]; cmv[rt][kt][1] = cp[1];
        }

    f32x4 acc[4][4];                    // [rt][nt] -- full 64x64 partial over 8 cells
    #pragma unroll
    for (int rt = 0; rt < 4; ++rt)
        #pragma unroll
        for (int nt = 0; nt < 4; ++nt) acc[rt][nt] = (f32x4){0.f,0.f,0.f,0.f};

    auto load_cell = [&](short8 (&bw)[2][4], int cidx) {
        const int g = chalf*32 + w*8 + ((cidx + xph) & 7);
        const short* wg = Wt + (size_t)g*4096;
        #pragma unroll
        for (int kt = 0; kt < 2; ++kt)
            #pragma unroll
            for (int nt = 0; nt < 4; ++nt)
                bw[kt][nt] = *(const short8*)(wg + (nt*16 + ln15)*64 + kt*32 + ln4*8);
    };
    auto compute_cell = [&](const short8 (&bw)[2][4], int cidx) {
        const int g = chalf*32 + w*8 + ((cidx + xph) & 7);
        #pragma unroll
        for (int rt = 0; rt < 4; ++rt) {
            short8 sf[2];
            #pragma unroll
            for (int kt = 0; kt < 2; ++kt)
                #pragma unroll
                for (int u = 0; u < 8; ++u) {
                    unsigned byte = ((u < 4 ? cmv[rt][kt][0] >> (8*u)
                                           : cmv[rt][kt][1] >> (8*(u-4))) & 255u);
                    sf[kt][u] = (byte == (unsigned)g) ? (short)0x3F80 : (short)0;
                }
            f32x4 pt[4];
            #pragma unroll
            for (int mt = 0; mt < 4; ++mt) pt[mt] = (f32x4){0.f,0.f,0.f,0.f};
            #pragma unroll
            for (int kt2 = 0; kt2 < 2; ++kt2)
                #pragma unroll
                for (int mt = 0; mt < 4; ++mt)
                    pt[mt] = __builtin_amdgcn_mfma_f32_16x16x32_bf16(hf2[mt][kt2], sf[kt2], pt[mt], 0, 0, 0);
            #pragma unroll
            for (int kt = 0; kt < 2; ++kt) {
                union { short8 s; unsigned u4[4]; } af;     // packed bf16 converts
                af.u4[0] = pk2(pt[2*kt    ][0], pt[2*kt    ][1]);
                af.u4[1] = pk2(pt[2*kt    ][2], pt[2*kt    ][3]);
                af.u4[2] = pk2(pt[2*kt + 1][0], pt[2*kt + 1][1]);
                af.u4[3] = pk2(pt[2*kt + 1][2], pt[2*kt + 1][3]);
                #pragma unroll
                for (int nt = 0; nt < 4; ++nt)
                    acc[rt][nt] = __builtin_amdgcn_mfma_f32_16x16x32_bf16(af.s, bw[kt][nt], acc[rt][nt], 0, 0, 0);
            }
        }
    };

    // double-buffered cell loop (verified R8 best)
    short8 bwA[2][4], bwB[2][4];
    load_cell(bwA, 0);
    #pragma unroll
    for (int cc = 0; cc < 8; cc += 2) {
        if (cc + 1 < 8) load_cell(bwB, cc + 1);
        compute_cell(bwA, cc);
        if (cc + 2 < 8) load_cell(bwA, cc + 2);
        if (cc + 1 < 8) compute_cell(bwB, cc + 1);
    }
    __syncthreads();                               // staging reads all hoisted

    // 2-step two-buffer combine: waves 0-1 -> Xs0, waves 2-3 -> Xs1
    float* Xs0 = (float*)smem;
    float* Xs1 = (float*)(smem + SM_XS1);
    for (int step = 0; step < 2; ++step) {
        if ((w & 1) == step) {
            float* Xs = (w < 2) ? Xs0 : Xs1;
            #pragma unroll
            for (int rt = 0; rt < 4; ++rt)
                #pragma unroll
                for (int nt = 0; nt < 4; ++nt)
                    #pragma unroll
                    for (int r = 0; r < 4; ++r) {
                        int row = rt*16 + ln4*4 + r;   // C/D: col=lane&15, row=(lane>>4)*4+reg
                        int col = nt*16 + ln15;
                        if (step == 0) Xs[row*68 + col]  = acc[rt][nt][r];
                        else           Xs[row*68 + col] += acc[rt][nt][r];
                    }
        }
        __syncthreads();
    }

    // write partial X for this cell-half (coalesced f32x4): no bias here
    {
        float* xp = Xpart + (size_t)b*4096;
        const int row = tid >> 2, c0 = (tid & 3)*16;
        #pragma unroll
        for (int q = 0; q < 4; ++q) {
            f32x4 v;
            #pragma unroll
            for (int u = 0; u < 4; ++u) {
                int o = row*68 + c0 + q*4 + u;
                v[u] = Xs0[o] + Xs1[o];
            }
            *(f32x4*)(xp + row*64 + c0 + q*4) = v;
        }
    }
}

// ---------------- K2: add halves + bias -> X, column partials ----------------
__global__ __launch_bounds__(256) void sp_combine(
    const float* __restrict__ Xpart, const float* __restrict__ bvec,
    float* __restrict__ X, float* __restrict__ partials)
{
    __shared__ float red1[16*64], red2[16*64];
    const int s = blockIdx.x, tid = threadIdx.x;
    const f32x4* Xa = (const f32x4*)(Xpart + (size_t)(2*s    )*4096);
    const f32x4* Xb = (const f32x4*)(Xpart + (size_t)(2*s + 1)*4096);
    f32x4* Xo = (f32x4*)(X + (size_t)s*4096);

    const int c0 = (tid & 15)*4;
    float s1[4] = {0.f,0.f,0.f,0.f}, s2[4] = {0.f,0.f,0.f,0.f};
    float bb[4];
    #pragma unroll
    for (int u = 0; u < 4; ++u) bb[u] = bvec[c0 + u];
    #pragma unroll
    for (int q = 0; q < 4; ++q) {
        int idx4 = q*256 + tid;                    // (idx4*4)&63 == c0
        f32x4 va = Xa[idx4], vb = Xb[idx4], v;
        #pragma unroll
        for (int u = 0; u < 4; ++u) {
            v[u] = va[u] + vb[u] + bb[u];
            s1[u] += v[u]; s2[u] += v[u]*v[u];
        }
        Xo[idx4] = v;
    }
    const int grp = tid >> 4;
    #pragma unroll
    for (int u = 0; u < 4; ++u) {
        red1[grp*64 + c0 + u] = s1[u];
        red2[grp*64 + c0 + u] = s2[u];
    }
    __syncthreads();
    if (tid < 128) {
        int hs = tid >> 6, c = tid & 63;
        const float* r0 = hs ? red2 : red1;
        float v = 0.f;
        #pragma unroll
        for (int g2 = 0; g2 < 16; ++g2) v += r0[g2*64 + c];
        partials[(size_t)s*128 + hs*64 + c] = v;   // [seq][slot]
    }
}

// ---------------- K3: redundant stats reduce + normalize + ReLU (verified R4+) ----------------
__global__ __launch_bounds__(256) void sp_finish(
    float* __restrict__ X, const float* __restrict__ partials,
    const float* __restrict__ gamma, const float* __restrict__ beta)
{
    __shared__ float sp0[128], sp1[128];
    __shared__ float scale[64], shift[64];
    const int b = blockIdx.x, tid = threadIdx.x;

    {   // sum 256 seq-partials; coalesced along slot
        const int slot = tid & 127, hb = tid >> 7;
        float v = 0.f;
        const float* p = partials + (size_t)hb*128*128 + slot;
        #pragma unroll 4
        for (int bb = 0; bb < 128; ++bb) v += p[(size_t)bb*128];
        (hb ? sp1 : sp0)[slot] = v;
    }
    __syncthreads();
    if (tid < 64) {
        const float inv_n = 1.0f / (float)NTOT;
        float s1 = sp0[tid] + sp1[tid];
        float s2 = sp0[64 + tid] + sp1[64 + tid];
        float mu  = s1 * inv_n;
        float var = s2 * inv_n - mu*mu;
        float sc  = gamma[tid] / sqrtf(var + EPSV);
        scale[tid] = sc;
        shift[tid] = beta[tid] - mu*sc;
    }
    __syncthreads();
    #pragma unroll
    for (int q = 0; q < 4; ++q) {
        size_t idx4 = (size_t)b*1024 + q*256 + tid;  // f32x4 units
        f32x4 v = ((f32x4*)X)[idx4];
        int c0 = ((int)idx4*4) & 63;
        #pragma unroll
        for (int u = 0; u < 4; ++u)
            v[u] = fmaxf(v[u]*scale[c0 + u] + shift[c0 + u], 0.0f);
        ((f32x4*)X)[idx4] = v;
    }
}

extern "C" void kernel_launch(void* const* d_in, const int* in_sizes, int n_in,
                              void* d_out, int out_size, void* d_ws, size_t ws_size,
                              hipStream_t stream)
{
    const float* h     = (const float*)d_in[0];
    // d_in[1] seq_start_end: provably uniform (reference only uses N//nseq)
    const float* pos   = (const float*)d_in[2];
    const float* W     = (const float*)d_in[3];
    const float* bvec  = (const float*)d_in[4];
    const float* gamma = (const float*)d_in[5];
    const float* beta  = (const float*)d_in[6];

    float* X        = (float*)d_out;
    short* Wt       = (short*)d_ws;                          // 512 KB bf16 W' (k-permuted)
    float* Xpart    = (float*)((char*)d_ws + 524288);        // 512*4096*4 = 8 MB
    float* partials = (float*)((char*)d_ws + 524288 + 8388608); // 128 KB

    sp_transpose<<<64,  256, 0, stream>>>(W, Wt);
    sp_main     <<<512, 256, 0, stream>>>(h, pos, Wt, Xpart);
    sp_combine  <<<NSEQ, 256, 0, stream>>>(Xpart, bvec, X, partials);
    sp_finish   <<<NSEQ, 256, 0, stream>>>(X, partials, gamma, beta);
}